// Round 17
// baseline (378.808 us; speedup 1.0000x reference)
//
#include <hip/hip_runtime.h>

#define N     4096
#define KB    8
#define RSZ   32
#define BIG   1e30f
#define YIDXf(j) ((j) + (((j) >> 4) << 2))   // padded float index

// lane l gets lane l-1's value; lane 0 (and only lane 0) gets `old`
#define DPP_SHR1(res, oldv, srcv)                                         \
    res = __int_as_float(__builtin_amdgcn_update_dpp(                     \
        __float_as_int(oldv), __float_as_int(srcv), 0x138, 0xF, 0xF, false));

// -------- bidirectional column-seam kernel (grid = 2), TPB=256/RR=16 ------
// WG 0: forward DP on cols 0..2047 (4096 rows); WG 1: same DP on
// (x,y reversed) == backward DP. Thread t owns 16 rows, runs chunk c (2 cols)
// at step s = t + 8*(t>>6) + c; 1024 chunks/thread, balanced.
// Fill = 255 + 24 = 279 steps (vs 567 at TPB=512): steps 1592 -> 1304, and
// essential op-ratio/step rises to ~81%. 4 waves = 1/SIMD: viable because the
// critical chain is pure-register (DPP handoff; ring preloaded per epoch; y
// prefetched TWO steps ahead so DS latency has a full step of slack).
// Sync invariants: producer(lane63,wave w) writes ring slot at step 72w+63+c,
// consumer(lane0,wave w+1) preloads it at the head of the NEXT epoch (write
// is always in a strictly earlier epoch; one barrier between). Slot reuse
// period 32 steps >> gap 8.

#define TPB3   256
#define RR3    16
#define NCHH   1024
#define STEPS3 1304            // last active step = 279 + 1023 = 1302

__global__ __launch_bounds__(TPB3, 1)
void dtw_half_v2(const float* __restrict__ xg, const float* __restrict__ yg,
                 float* __restrict__ ws, int* __restrict__ cnt,
                 float* __restrict__ out) {
    __shared__ float  ylds[2048 + 2048 / 4 + 4];   // 10 KB
    __shared__ float2 ring2[3][RSZ];               // 768 B
    __shared__ float  red[4];

    const int t = threadIdx.x, lane = t & 63, w = t >> 6;
    const int b = blockIdx.x;                      // 0 = fwd, 1 = bwd(reversed)

    for (int j = t; j < 2048; j += TPB3)
        ylds[YIDXf(j)] = b ? yg[N - 1 - j] : yg[j];

    float x[RR3], carry[RR3];
    const int i0 = t * RR3;
#pragma unroll
    for (int r = 0; r < RR3; ++r) {
        x[r] = b ? xg[N - 1 - (i0 + r)] : xg[i0 + r];
        carry[r] = BIG;
    }

    float diagc = (t == 0) ? 0.0f : BIG;   // (0,0): min3(BIG,BIG,0)=0 -> D[0][0]=c
    const int start = t + KB * w;
    const bool wring = (lane == 63) && (w < 3);

    float bt0 = BIG, bt1 = BIG;
    float nb0 = BIG, nb1 = BIG;

    __syncthreads();

    // y double-prefetch: cur for step s, nxt arriving for step s+1
    float2 yv_cur, yv_nxt;
    {
        int c0 = 0 - start; c0 = c0 < 0 ? 0 : c0;
        int c1 = 1 - start; c1 = c1 < 0 ? 0 : c1;
        yv_cur = *(const float2*)&ylds[YIDXf(2 * c0)];
        yv_nxt = *(const float2*)&ylds[YIDXf(2 * c1)];
    }

    for (int sb = 0; sb < STEPS3; sb += KB) {
        // epoch head: preload this epoch's 8 ring slots (wave-uniform bcast)
        float2 nbring[KB];
        if (w > 0) {
            const int base = sb + 1 - 72 * w;
#pragma unroll
            for (int k = 0; k < KB; ++k)
                nbring[k] = ring2[w - 1][(base + k) & (RSZ - 1)];
        } else {
#pragma unroll
            for (int k = 0; k < KB; ++k)
                nbring[k] = make_float2(BIG, BIG);
        }

#pragma unroll
        for (int ss = 0; ss < KB; ++ss) {
            const int s = sb + ss;
            const int c = s - start;

            if ((unsigned)c < (unsigned)NCHH) {
#define DO_COL(YC, NB, DG, BT)                                            \
                { float up = (NB), dgv = (DG);                            \
                  _Pragma("unroll")                                       \
                  for (int r = 0; r < RR3; ++r) {                         \
                      const float old = carry[r];                         \
                      const float v = fabsf(x[r] - (YC)) +                \
                                      fminf(up, fminf(old, dgv));         \
                      carry[r] = v; up = v; dgv = old;                    \
                  }                                                       \
                  (BT) = up; }
                DO_COL(yv_cur.x, nb0, diagc, bt0)
                DO_COL(yv_cur.y, nb1, nb0,   bt1)
#undef DO_COL
                diagc = nb1;
                if (wring)
                    ring2[w][c & (RSZ - 1)] = make_float2(bt0, bt1);
            }

            // tail: register handoff + rotate y prefetch (2 steps ahead)
            {
                const float2 oldv = nbring[ss];
                DPP_SHR1(nb0, oldv.x, bt0)
                DPP_SHR1(nb1, oldv.y, bt1)
                yv_cur = yv_nxt;
                int cn = c + 2;
                cn = cn < 0 ? 0 : (cn > NCHH - 1 ? NCHH - 1 : cn);
                yv_nxt = *(const float2*)&ylds[YIDXf(2 * cn)];
            }
            asm volatile("" ::: "memory");
        }
        __syncthreads();   // epoch barrier: orders all ring traffic
    }

    // publish column-2047 slice (carry[] untouched since last chunk)
    {
        float4* dst = (float4*)(ws + (size_t)b * 4096 + i0);
#pragma unroll
        for (int q = 0; q < 4; ++q)
            dst[q] = make_float4(carry[4 * q], carry[4 * q + 1],
                                 carry[4 * q + 2], carry[4 * q + 3]);
    }
    __syncthreads();

    // device-scope rendezvous (both WGs co-resident: grid=2)
    if (t == 0) {
        __hip_atomic_fetch_add(cnt, 1, __ATOMIC_ACQ_REL, __HIP_MEMORY_SCOPE_AGENT);
        while (__hip_atomic_load(cnt, __ATOMIC_ACQUIRE,
                                 __HIP_MEMORY_SCOPE_AGENT) < 2) {}
    }
    __syncthreads();

    if (b == 1) {
        // D = min_i [ F[i] + min(B0, B1) ], B0 = Brev[4095-i], B1 = Brev[4094-i]
        float m = BIG;
#pragma unroll
        for (int r = 0; r < RR3; ++r) {
            const int i = i0 + r;
            const float F  = ws[i];
            const float B0 = ws[4096 + (N - 1 - i)];
            const float B1 = (i < N - 1) ? ws[4096 + (N - 2 - i)] : BIG;
            m = fminf(m, F + fminf(B0, B1));
        }
#pragma unroll
        for (int o = 32; o >= 1; o >>= 1) m = fminf(m, __shfl_xor(m, o));
        if (lane == 0) red[w] = m;
        __syncthreads();
        if (t == 0)
            out[0] = fminf(fminf(red[0], red[1]), fminf(red[2], red[3]));
    }
}

// ---------------- fallback: R11 single-WG kernel (proven, 500us) ----------
#define TPB  512
#define C    4
#define NCH  (N / C)
#define NW   (TPB / 64)
#define YIDX4(c) (((c) << 2) + (((c) >> 2) << 2))
__global__ __launch_bounds__(TPB, 1)
void dtw_diet(const float* __restrict__ xg, const float* __restrict__ yg,
              float* __restrict__ out) {
    __shared__ float  ylds[N + N / 4 + 4];
    __shared__ float4 bot4[2][TPB];
    __shared__ float4 ring4[NW - 1][RSZ];
    __shared__ float4 bigv;

    const int t = threadIdx.x, lane = t & 63, w = t >> 6;
    for (int j4 = t * 4; j4 < N; j4 += TPB * 4)
        *(float4*)&ylds[YIDX4(j4 >> 2)] = *(const float4*)&yg[j4];
    if (t == 0) bigv = make_float4(BIG, BIG, BIG, BIG);

    float x[8], carry[8];
    const int i0 = t * 8;
#pragma unroll
    for (int r = 0; r < 8; ++r) { x[r] = xg[i0 + r]; carry[r] = BIG; }
    float diagc = (t == 0) ? 0.0f : BIG;
    const int start = t + KB * w;
    const bool wring = (lane == 63) && (w < NW - 1);
    const int  tm1 = (t > 0) ? t - 1 : 0;
    __syncthreads();

    float4 nb4 = make_float4(BIG, BIG, BIG, BIG);
    float4 yv = *(const float4*)&ylds[0];

    for (int sb = 0; sb < 1592; sb += KB) {
        for (int ss = 0; ss < KB; ++ss) {
            const int s = sb + ss;
            const int c = s - start;
            if ((unsigned)c < (unsigned)NCH) {
                float bt0, bt1, bt2, bt3;
#define DO_COL(YC, NB, DG, BT)                                            \
                { float up = (NB), dgv = (DG);                            \
                  _Pragma("unroll")                                       \
                  for (int r = 0; r < 8; ++r) {                           \
                      const float old = carry[r];                         \
                      const float v = fabsf(x[r] - (YC)) +                \
                                      fminf(up, fminf(old, dgv));         \
                      carry[r] = v; up = v; dgv = old;                    \
                  }                                                       \
                  (BT) = up; }
                DO_COL(yv.x, nb4.x, diagc, bt0)
                DO_COL(yv.y, nb4.y, nb4.x, bt1)
                DO_COL(yv.z, nb4.z, nb4.y, bt2)
                DO_COL(yv.w, nb4.w, nb4.z, bt3)
#undef DO_COL
                diagc = nb4.w;
                float4* wp = wring ? &ring4[w][c & (RSZ - 1)]
                                   : &bot4[s & 1][t];
                *wp = make_float4(bt0, bt1, bt2, bt3);
            }
            {
                const int c1 = c + 1;
                const float4* rp;
                if (lane == 0)
                    rp = (w == 0) ? &bigv : &ring4[w - 1][c1 & (RSZ - 1)];
                else
                    rp = &bot4[s & 1][tm1];
                nb4 = *rp;
                const unsigned cc = min((unsigned)c1, (unsigned)(NCH - 1));
                yv = *(const float4*)&ylds[YIDX4(cc)];
            }
            asm volatile("" ::: "memory");
        }
        __syncthreads();
    }
    if (t == TPB - 1) out[0] = carry[7];
}

extern "C" void kernel_launch(void* const* d_in, const int* in_sizes, int n_in,
                              void* d_out, int out_size, void* d_ws, size_t ws_size,
                              hipStream_t stream) {
    const float* src = (const float*)d_in[0];
    const float* tgt = (const float*)d_in[1];
    float* out = (float*)d_out;

    const size_t req = 8192 * sizeof(float) + 64;   // seams + arrive counter
    if (ws_size >= req) {
        float* ws  = (float*)d_ws;
        int*   cnt = (int*)((char*)d_ws + 8192 * sizeof(float));
        hipMemsetAsync(cnt, 0, 64, stream);         // fresh counter every call
        hipLaunchKernelGGL(dtw_half_v2, dim3(2), dim3(TPB3), 0, stream,
                           src, tgt, ws, cnt, out);
    } else {
        hipLaunchKernelGGL(dtw_diet, dim3(1), dim3(TPB), 0, stream,
                           src, tgt, out);
    }
}

// Round 18
// 332.624 us; speedup vs baseline: 1.1388x; 1.1388x over previous
//
#include <hip/hip_runtime.h>

#define N     4096
#define TPB   512
#define KB    8
#define RSZ   32
#define NW    (TPB / 64)
#define BIG   1e30f
#define YIDXf(j) ((j) + (((j) >> 4) << 2))           // padded float index
#define NCHH   1024           // 2048 cols / C=2
#define STEPSH 1592           // last active step = 567 + 1023 = 1590

// lane l gets lane l-1's value; lane 0 (and only lane 0) gets `old`
#define DPP_SHR1(res, oldv, srcv)                                         \
    res = __int_as_float(__builtin_amdgcn_update_dpp(                     \
        __float_as_int(oldv), __float_as_int(srcv), 0x138, 0xF, 0xF, false));

// ---------------- bidirectional column-seam kernel (grid = 2), C=2 -------
// Block 0: forward DP on cols 0..2047 (4096 rows); block 1: same DP on
// (x,y reversed) == backward DP. Thread t owns 8 rows, runs chunk c (2 cols)
// at step s = t + 8*(t/64) + c; balanced 1024 chunks/thread.
// Handoff lane->lane: v_mov_dpp wave_shr:1 (pure register). Lane 0's
// cross-wave value rides the DPP `old` operand, preloaded once per epoch
// from the wave-boundary LDS ring (slots for epoch e+1 are all written
// during epoch e; producer->consumer gap is 9 steps > KB=8; slot reuse
// period 32 steps >> 9). 2 waves/SIMD hide chain+DS latency (R17 confirmed
// 1 wave/SIMD exposes ~450cy/step). Measured best: 332.6us (R16).

__global__ __launch_bounds__(TPB, 1)
void dtw_half_c2(const float* __restrict__ xg, const float* __restrict__ yg,
                 float* __restrict__ ws, int* __restrict__ cnt,
                 float* __restrict__ out) {
    __shared__ float  ylds[2048 + 2048 / 4 + 4];   // 10 KB
    __shared__ float2 ring2[NW - 1][RSZ];          // 1.75 KB
    __shared__ float  red[NW];

    const int t = threadIdx.x, lane = t & 63, w = t >> 6;
    const int b = blockIdx.x;                      // 0 = fwd, 1 = bwd(reversed)

    for (int j = t; j < 2048; j += TPB)
        ylds[YIDXf(j)] = b ? yg[N - 1 - j] : yg[j];

    float x[8], carry[8];
    const int i0 = t * 8;
#pragma unroll
    for (int r = 0; r < 8; ++r) {
        x[r] = b ? xg[N - 1 - (i0 + r)] : xg[i0 + r];
        carry[r] = BIG;
    }

    float diagc = (t == 0) ? 0.0f : BIG;   // (0,0): min3(BIG,BIG,0)=0 -> D[0][0]=c
    const int start = t + KB * w;
    const bool wring = (lane == 63) && (w < NW - 1);

    float bt0 = BIG, bt1 = BIG;
    float nb0 = BIG, nb1 = BIG;

    __syncthreads();
    float2 yv = *(const float2*)&ylds[0];

    for (int sb = 0; sb < STEPSH; sb += KB) {
        // epoch head: preload this epoch's 8 ring slots (wave-uniform bcast).
        // slot for phase ss: (sb+ss+1 - 72w) & 31; all written in prior epochs.
        float2 nbring[KB];
        if (w > 0) {
            const int base = sb + 1 - 72 * w;
#pragma unroll
            for (int k = 0; k < KB; ++k)
                nbring[k] = ring2[w - 1][(base + k) & (RSZ - 1)];
        } else {
#pragma unroll
            for (int k = 0; k < KB; ++k)
                nbring[k] = make_float2(BIG, BIG);
        }

#pragma unroll
        for (int ss = 0; ss < KB; ++ss) {
            const int s = sb + ss;
            const int c = s - start;

            if ((unsigned)c < (unsigned)NCHH) {
#define DO_COL(YC, NB, DG, BT)                                            \
                { float up = (NB), dgv = (DG);                            \
                  _Pragma("unroll")                                       \
                  for (int r = 0; r < 8; ++r) {                           \
                      const float old = carry[r];                         \
                      const float v = fabsf(x[r] - (YC)) +                \
                                      fminf(up, fminf(old, dgv));         \
                      carry[r] = v; up = v; dgv = old;                    \
                  }                                                       \
                  (BT) = up; }
                DO_COL(yv.x, nb0, diagc, bt0)
                DO_COL(yv.y, nb1, nb0,   bt1)
#undef DO_COL
                diagc = nb1;
                if (wring)
                    ring2[w][c & (RSZ - 1)] = make_float2(bt0, bt1);
            }

            // tail: register handoff + y prefetch for step s+1
            {
                const float2 oldv = nbring[ss];
                DPP_SHR1(nb0, oldv.x, bt0)
                DPP_SHR1(nb1, oldv.y, bt1)
                const unsigned cc = min((unsigned)(c + 1), (unsigned)(NCHH - 1));
                yv = *(const float2*)&ylds[YIDXf(2 * cc)];
            }
            asm volatile("" ::: "memory");
        }
        __syncthreads();   // epoch barrier: orders all ring traffic
    }

    // publish column-2047 slice (carry[] untouched since last chunk)
    {
        float4* dst = (float4*)(ws + (size_t)b * 4096 + i0);
        dst[0] = make_float4(carry[0], carry[1], carry[2], carry[3]);
        dst[1] = make_float4(carry[4], carry[5], carry[6], carry[7]);
    }
    __syncthreads();

    // device-scope rendezvous (both WGs co-resident: grid=2)
    if (t == 0) {
        __hip_atomic_fetch_add(cnt, 1, __ATOMIC_ACQ_REL, __HIP_MEMORY_SCOPE_AGENT);
        while (__hip_atomic_load(cnt, __ATOMIC_ACQUIRE,
                                 __HIP_MEMORY_SCOPE_AGENT) < 2) {}
    }
    __syncthreads();

    if (b == 1) {
        // D = min_i [ F[i] + min(B0, B1) ], B0 = Brev[4095-i], B1 = Brev[4094-i]
        const float4 f0 = *(const float4*)&ws[i0];
        const float4 f1 = *(const float4*)&ws[i0 + 4];
        const float4 ba = *(const float4*)&ws[4096 + (4088 - i0)]; // r=7..4 rev
        const float4 bb = *(const float4*)&ws[4096 + (4092 - i0)]; // r=3..0 rev
        const float F[8]  = {f0.x, f0.y, f0.z, f0.w, f1.x, f1.y, f1.z, f1.w};
        const float B0[8] = {bb.w, bb.z, bb.y, bb.x, ba.w, ba.z, ba.y, ba.x};
        const float b1_7 = (i0 + 7 < N - 1) ? ws[4096 + (4087 - i0)] : BIG;
        const float B1[8] = {B0[1], B0[2], B0[3], B0[4], B0[5], B0[6], B0[7], b1_7};
        float m = BIG;
#pragma unroll
        for (int r = 0; r < 8; ++r)
            m = fminf(m, F[r] + fminf(B0[r], B1[r]));
#pragma unroll
        for (int o = 32; o >= 1; o >>= 1) m = fminf(m, __shfl_xor(m, o));
        if (lane == 0) red[w] = m;
        __syncthreads();
        if (t == 0) {
            float mm = red[0];
#pragma unroll
            for (int k = 1; k < NW; ++k) mm = fminf(mm, red[k]);
            out[0] = mm;
        }
    }
}

// ---------------- fallback: R11 single-WG kernel (proven, 500us) ----------
#define C    4
#define NCH  (N / C)
#define YIDX4(c) (((c) << 2) + (((c) >> 2) << 2))
__global__ __launch_bounds__(TPB, 1)
void dtw_diet(const float* __restrict__ xg, const float* __restrict__ yg,
              float* __restrict__ out) {
    __shared__ float  ylds[N + N / 4 + 4];
    __shared__ float4 bot4[2][TPB];
    __shared__ float4 ring4[NW - 1][RSZ];
    __shared__ float4 bigv;

    const int t = threadIdx.x, lane = t & 63, w = t >> 6;
    for (int j4 = t * 4; j4 < N; j4 += TPB * 4)
        *(float4*)&ylds[YIDX4(j4 >> 2)] = *(const float4*)&yg[j4];
    if (t == 0) bigv = make_float4(BIG, BIG, BIG, BIG);

    float x[8], carry[8];
    const int i0 = t * 8;
#pragma unroll
    for (int r = 0; r < 8; ++r) { x[r] = xg[i0 + r]; carry[r] = BIG; }
    float diagc = (t == 0) ? 0.0f : BIG;
    const int start = t + KB * w;
    const bool wring = (lane == 63) && (w < NW - 1);
    const int  tm1 = (t > 0) ? t - 1 : 0;
    __syncthreads();

    float4 nb4 = make_float4(BIG, BIG, BIG, BIG);
    float4 yv = *(const float4*)&ylds[0];

    for (int sb = 0; sb < 1592; sb += KB) {
        for (int ss = 0; ss < KB; ++ss) {
            const int s = sb + ss;
            const int c = s - start;
            if ((unsigned)c < (unsigned)NCH) {
                float bt0, bt1, bt2, bt3;
#define DO_COL(YC, NB, DG, BT)                                            \
                { float up = (NB), dgv = (DG);                            \
                  _Pragma("unroll")                                       \
                  for (int r = 0; r < 8; ++r) {                           \
                      const float old = carry[r];                         \
                      const float v = fabsf(x[r] - (YC)) +                \
                                      fminf(up, fminf(old, dgv));         \
                      carry[r] = v; up = v; dgv = old;                    \
                  }                                                       \
                  (BT) = up; }
                DO_COL(yv.x, nb4.x, diagc, bt0)
                DO_COL(yv.y, nb4.y, nb4.x, bt1)
                DO_COL(yv.z, nb4.z, nb4.y, bt2)
                DO_COL(yv.w, nb4.w, nb4.z, bt3)
#undef DO_COL
                diagc = nb4.w;
                float4* wp = wring ? &ring4[w][c & (RSZ - 1)]
                                   : &bot4[s & 1][t];
                *wp = make_float4(bt0, bt1, bt2, bt3);
            }
            {
                const int c1 = c + 1;
                const float4* rp;
                if (lane == 0)
                    rp = (w == 0) ? &bigv : &ring4[w - 1][c1 & (RSZ - 1)];
                else
                    rp = &bot4[s & 1][tm1];
                nb4 = *rp;
                const unsigned cc = min((unsigned)c1, (unsigned)(NCH - 1));
                yv = *(const float4*)&ylds[YIDX4(cc)];
            }
            asm volatile("" ::: "memory");
        }
        __syncthreads();
    }
    if (t == TPB - 1) out[0] = carry[7];
}

extern "C" void kernel_launch(void* const* d_in, const int* in_sizes, int n_in,
                              void* d_out, int out_size, void* d_ws, size_t ws_size,
                              hipStream_t stream) {
    const float* src = (const float*)d_in[0];
    const float* tgt = (const float*)d_in[1];
    float* out = (float*)d_out;

    const size_t req = 8192 * sizeof(float) + 64;   // seams + arrive counter
    if (ws_size >= req) {
        float* ws  = (float*)d_ws;
        int*   cnt = (int*)((char*)d_ws + 8192 * sizeof(float));
        hipMemsetAsync(cnt, 0, 64, stream);         // fresh counter every call
        hipLaunchKernelGGL(dtw_half_c2, dim3(2), dim3(TPB), 0, stream,
                           src, tgt, ws, cnt, out);
    } else {
        hipLaunchKernelGGL(dtw_diet, dim3(1), dim3(TPB), 0, stream,
                           src, tgt, out);
    }
}